// Round 11
// baseline (3064.547 us; speedup 1.0000x reference)
//
#include <hip/hip_runtime.h>
#include <math.h>

#define BB 8
#define NN 2048
#define KNNK 8
#define OBJ 224
#define HWD (OBJ*OBJ)

// ---------------- workspace layout (float units) ----------------
constexpr size_t RESB_SZ = (size_t)HWD*64;        // 3,211,264 floats (12.85 MB)
constexpr size_t F_SZ    = (size_t)BB*NN*64;
constexpr size_t F0_SZ   = (size_t)BB*NN*8;
constexpr size_t RES_OFF = 0;
constexpr size_t H1_OFF  = RESB_SZ;
constexpr size_t F_OFF   = 2*RESB_SZ;
constexpr size_t F0_OFF  = F_OFF + F_SZ;
constexpr size_t BP_OFF  = F0_OFF + F0_SZ;        // 128 floats reserved: per-batch params
constexpr size_t GS_OFF  = BP_OFF + 128;          // 64 floats: group sum/sumsq
constexpr size_t GM_OFF  = GS_OFF + 64;           // 64 floats: mu/rsig
constexpr size_t WT1_OFF = GM_OFF + 64;           // 36864 transposed conv1 w
constexpr size_t WT2_OFF = WT1_OFF + 36864;       // 36864 transposed conv2 w
constexpr size_t INT_OFF = WT2_OFF + 36864;       // ints: lin[B*N*9], nidx[B*N*8]

// ---------------- K0: transpose conv weights [O][C][3][3] -> [k][C][O] ----
__global__ void k0_wt(const float* __restrict__ w, float* __restrict__ wt) {
    int i = blockIdx.x*256 + threadIdx.x;
    if (i >= 64*64*9) return;
    int o = i/576, c = (i/9)%64, kk = i%9;
    wt[(size_t)(kk*64 + c)*64 + o] = w[i];
}

// ---------------- K1: per-batch grid params — fast-math (arcp) f32 -------
// Elimination record: faithful f32-IEEE (R8, bit-exact incl. pinned div +
// np-einsum KNN) FAILED at 0.1326; full f64 (R7) FAILED at 0.1174; grid-
// const reciprocal (R10) = bit-identical to IEEE. R7 moving the max proves
// the floor((x-min)/grid) site is live. Remaining semantics: compiled
// fast-math — LLVM arcp rewrites the broadcast divide x/grid into
// x * fl(1/grid) (reciprocal hoisted, one IEEE division). Every batch's
// argmax point sits at q ~ 221 knife-edge; the reciprocal-multiply rounds
// q differently than division -> different floor in ~half the batches.
__global__ void k1_params(const float* __restrict__ pc, float* __restrict__ bparam) {
    __shared__ float r0[256], r1[256], r2[256], r3[256];
    __shared__ float sh[4];
    int b = blockIdx.x, t = threadIdx.x;
    const float* p = pc + (size_t)b*NN*3;
    float mnx=1e30f, mxx=-1e30f, mny=1e30f, mxy=-1e30f;
    for (int n=t; n<NN; n+=256) {
        float x=p[3*n], y=p[3*n+1];
        mnx=fminf(mnx,x); mxx=fmaxf(mxx,x); mny=fminf(mny,y); mxy=fmaxf(mxy,y);
    }
    r0[t]=mnx; r1[t]=mxx; r2[t]=mny; r3[t]=mxy;
    __syncthreads();
    for (int s=128; s>0; s>>=1) {
        if (t<s) { r0[t]=fminf(r0[t],r0[t+s]); r1[t]=fmaxf(r1[t],r1[t+s]);
                   r2[t]=fminf(r2[t],r2[t+s]); r3[t]=fmaxf(r3[t],r3[t+s]); }
        __syncthreads();
    }
    if (t==0) {
        float rx = __fsub_rn(r1[0], r0[0]);          // pc_range: one f32 rounding
        float ry = __fsub_rn(r3[0], r2[0]);
        sh[0]=r0[0]; sh[1]=r2[0];
        // grid = R * fl(1/221)  (bit-equal to IEEE div on this data — R10)
        float c221 = __fdiv_rn(1.0f, (float)(OBJ-3));
        float grid = __fmul_rn(fmaxf(rx,ry), c221);
        sh[2] = grid;
        sh[3] = __fdiv_rn(1.0f, grid);               // hoisted reciprocal (arcp)
    }
    __syncthreads();
    float minx=sh[0], miny=sh[1], rgrid=sh[3];
    mnx=1e30f; mxx=-1e30f; mny=1e30f; mxy=-1e30f;
    for (int n=t; n<NN; n+=256) {
        float ix = floorf(__fmul_rn(__fsub_rn(p[3*n],   minx), rgrid));
        float iy = floorf(__fmul_rn(__fsub_rn(p[3*n+1], miny), rgrid));
        mnx=fminf(mnx,ix); mxx=fmaxf(mxx,ix); mny=fminf(mny,iy); mxy=fmaxf(mxy,iy);
    }
    __syncthreads();
    r0[t]=mnx; r1[t]=mxx; r2[t]=mny; r3[t]=mxy;
    __syncthreads();
    for (int s=128; s>0; s>>=1) {
        if (t<s) { r0[t]=fminf(r0[t],r0[t+s]); r1[t]=fmaxf(r1[t],r1[t+s]);
                   r2[t]=fminf(r2[t],r2[t+s]); r3[t]=fmaxf(r3[t],r3[t+s]); }
        __syncthreads();
    }
    if (t==0) {
        // max(dense)=max_ix+2, min(dense)=min_ix; sums are exact small ints in f32
        float cx = floorf((r1[0] + 2.0f + r0[0]) * 0.5f);
        float cy = floorf((r3[0] + 2.0f + r2[0]) * 0.5f);
        bparam[b*8+0]=minx; bparam[b*8+1]=miny; bparam[b*8+2]=sh[3];  // store rgrid
        bparam[b*8+3]=112.0f - cx - 1.0f;
        bparam[b*8+4]=112.0f - cy - 1.0f;
    }
}

// ---------------- K2: linear grid indices — fast-math (arcp) f32 ---------
__global__ void k2_lin(const float* __restrict__ pc, const float* __restrict__ bparam,
                       int* __restrict__ lin) {
    int i = blockIdx.x*256 + threadIdx.x;     // b*N+n
    if (i >= BB*NN) return;
    int b = i / NN;
    float x = pc[(size_t)i*3], y = pc[(size_t)i*3+1];
    float minx=bparam[b*8], miny=bparam[b*8+1], rgrid=bparam[b*8+2];
    float offx=bparam[b*8+3], offy=bparam[b*8+4];
    float ix = floorf(__fmul_rn(__fsub_rn(x, minx), rgrid));
    float iy = floorf(__fmul_rn(__fsub_rn(y, miny), rgrid));
    const float o9x[9] = {-1,-1,-1, 0,0,0, 1,1,1};
    const float o9y[9] = {-1, 0, 1,-1,0,1,-1,0,1};
#pragma unroll
    for (int j=0; j<9; ++j) {
        float dx = ix + o9x[j] + 1.0f + offx;     // exact small-int f32
        float dy = iy + o9y[j] + 1.0f + offy;
        dx += (dx < 0.f ? 1.f : 0.f) - (dx > 223.f ? 1.f : 0.f);
        dy += (dy < 0.f ? 1.f : 0.f) - (dy > 223.f ? 1.f : 0.f);
        lin[(size_t)i*9 + j] = (int)(dx*224.f + dy);   // <=50175: exact
    }
}

// ---------------- K3: f0 = pc @ w_in^T + b_in ----------------
__global__ void k3_f0(const float* __restrict__ pc, const float* __restrict__ w_in,
                      const float* __restrict__ b_in, float* __restrict__ f0) {
    int i = blockIdx.x*256 + threadIdx.x;     // (b*N+n)*8+o
    if (i >= BB*NN*8) return;
    int o = i & 7; int bn = i >> 3;
    float x=pc[(size_t)bn*3], y=pc[(size_t)bn*3+1], z=pc[(size_t)bn*3+2];
    f0[i] = x*w_in[o*3] + y*w_in[o*3+1] + z*w_in[o*3+2] + b_in[o];
}

// ---------------- K4: brute-force KNN — f32, set-stable ------------------
// Sets bit-identical across asc-FMA/asc-unfused/desc-unfused/f64-true
// (R1-R4): rank-8/9 gaps exceed the ~5e-7 reorder noise, so these ARE the
// reference's neighbor sets; downstream use (GN sum, max_k) is
// order-invariant.
__global__ __launch_bounds__(256) void k4_knn(const float* __restrict__ pc,
                                              int* __restrict__ nidx) {
    __shared__ float4 pts[NN];
    int b = blockIdx.y, t = threadIdx.x;
    const float* p = pc + (size_t)b*NN*3;
    for (int m=t; m<NN; m+=256) {
        float x=p[3*m], y=p[3*m+1], z=p[3*m+2];
        float sq = __fadd_rn(__fadd_rn(__fmul_rn(x,x), __fmul_rn(y,y)), __fmul_rn(z,z));
        pts[m] = make_float4(x, y, z, sq);
    }
    __syncthreads();
    int n = blockIdx.x*256 + t;
    float4 me = pts[n];
    float bd[KNNK]; int bi[KNNK];
#pragma unroll
    for (int j=0; j<KNNK; ++j) { bd[j]=1e30f; bi[j]=0; }
    for (int m=0; m<NN; ++m) {
        float4 q = pts[m];
        float dot = __fadd_rn(__fadd_rn(__fmul_rn(me.z,q.z), __fmul_rn(me.y,q.y)),
                              __fmul_rn(me.x,q.x));
        float d = __fsub_rn(__fadd_rn(me.w, q.w), __fmul_rn(2.0f, dot));
        if (d < bd[KNNK-1]) {
            float v=d; int vi=m;
#pragma unroll
            for (int j=0; j<KNNK; ++j) {
                if (v < bd[j]) { float tv=bd[j]; int ti=bi[j]; bd[j]=v; bi[j]=vi; v=tv; vi=ti; }
            }
        }
    }
#pragma unroll
    for (int j=0; j<KNNK; ++j) nidx[((size_t)b*NN + n)*KNNK + j] = bi[j];
}

// ---------------- feat builder (shared by K5/K6) ----------------
__device__ __forceinline__ void build_feat(int t, int b, int n0,
        const float* __restrict__ f0, const int* __restrict__ nidx,
        float feat[4][8][16]) {
    int pt = t >> 6, k = (t >> 3) & 7, c = t & 7;
    int n  = n0 + pt;
    int nb = nidx[((size_t)b*NN + n)*8 + k];
    float f0c = f0[((size_t)b*NN + n)*8 + c];
    float fnc = f0[((size_t)b*NN + nb)*8 + c];
    feat[pt][k][c]   = fnc - f0c;
    feat[pt][k][c+8] = f0c;
}

// ---------------- K5: GroupNorm stats pass ----------------
__global__ __launch_bounds__(256) void k5_stats(const float* __restrict__ f0,
        const int* __restrict__ nidx, const float* __restrict__ w_graph,
        float* __restrict__ gsum) {
    __shared__ float wgT[16*64];
    __shared__ float feat[4][8][16];
    __shared__ float part[4][4][2];
    int t = threadIdx.x;
    for (int i=t; i<1024; i+=256) wgT[(i&15)*64 + (i>>4)] = w_graph[i];
    int blk = blockIdx.x;
    int b = blk >> 9, n0 = (blk & 511)*4;
    build_feat(t, b, n0, f0, nidx, feat);
    __syncthreads();
    int pt = t >> 6, o = t & 63;
    float s = 0.f, s2 = 0.f;
#pragma unroll
    for (int k=0; k<8; ++k) {
        float g = 0.f;
#pragma unroll
        for (int c=0; c<16; ++c) g = fmaf(feat[pt][k][c], wgT[c*64+o], g);
        s += g; s2 += g*g;
    }
#pragma unroll
    for (int off=8; off; off>>=1) {
        s  += __shfl_down(s,  off, 16);
        s2 += __shfl_down(s2, off, 16);
    }
    if ((o & 15) == 0) { part[pt][o>>4][0] = s; part[pt][o>>4][1] = s2; }
    __syncthreads();
    if (t < 8) {
        int grp = t >> 1, which = t & 1;
        float v = part[0][grp][which] + part[1][grp][which]
                + part[2][grp][which] + part[3][grp][which];
        atomicAdd(&gsum[(b*4+grp)*2 + which], v);
    }
}

__global__ void k5b_finalize(const float* __restrict__ gsum, float* __restrict__ gmu) {
    int t = threadIdx.x;
    if (t < 32) {
        const float cnt = (float)(NN*KNNK*16);
        float mu = gsum[t*2] / cnt;
        float var = gsum[t*2+1] / cnt - mu*mu;
        gmu[t*2]   = mu;
        gmu[t*2+1] = 1.0f / sqrtf(var + 1e-5f);
    }
}

// ---------------- K6: normalize + leaky + max_k + proj ----------------
__global__ __launch_bounds__(256) void k6_point(const float* __restrict__ f0,
        const int* __restrict__ nidx, const float* __restrict__ w_graph,
        const float* __restrict__ gmu, const float* __restrict__ gn_g,
        const float* __restrict__ gn_b, const float* __restrict__ w_proj,
        const float* __restrict__ b_proj, float* __restrict__ f) {
    __shared__ float wgT[16*64];
    __shared__ float wpT[64*64];
    __shared__ float feat[4][8][16];
    __shared__ float gmax_s[4][64];
    int t = threadIdx.x;
    for (int i=t; i<1024; i+=256) wgT[(i&15)*64 + (i>>4)] = w_graph[i];
    for (int i=t; i<4096; i+=256) wpT[(i&63)*64 + (i>>6)] = w_proj[i];
    int blk = blockIdx.x;
    int b = blk >> 9, n0 = (blk & 511)*4;
    build_feat(t, b, n0, f0, nidx, feat);
    __syncthreads();
    int pt = t >> 6, o = t & 63;
    int grp = o >> 4;
    float mu = gmu[(b*4+grp)*2], rsig = gmu[(b*4+grp)*2+1];
    float ga = gn_g[o], be = gn_b[o];
    float gm = -1e30f;
#pragma unroll
    for (int k=0; k<8; ++k) {
        float g = 0.f;
#pragma unroll
        for (int c=0; c<16; ++c) g = fmaf(feat[pt][k][c], wgT[c*64+o], g);
        float v = (g - mu)*rsig*ga + be;
        v = (v >= 0.f) ? v : 0.2f*v;
        gm = fmaxf(gm, v);
    }
    gmax_s[pt][o] = gm;
    __syncthreads();
    float acc = b_proj[o];
#pragma unroll
    for (int c=0; c<64; ++c) acc = fmaf(gmax_s[pt][c], wpT[c*64+o], acc);
    f[((size_t)b*NN + n0 + pt)*64 + o] = acc;
}

// ---------------- K7: scatter-sum onto NHWC grid (single batch) ----------
__global__ __launch_bounds__(256) void k7_scatter(const float* __restrict__ f,
        const int* __restrict__ lin, float* __restrict__ res) {
    int blk = blockIdx.x, t = threadIdx.x;
    int b = blk >> 9;
    int n = (blk & 511)*4 + (t >> 6);
    int o = t & 63;
    size_t bn = (size_t)b*NN + n;
    float v = f[bn*64 + o];
#pragma unroll
    for (int j=0; j<9; ++j) {
        int cell = lin[bn*9 + j];
        if (cell >= 0 && cell < HWD)
            atomicAdd(&res[((size_t)b*HWD + cell)*64 + o], v);
    }
}

// ---------------- K8: conv3x3 + scale/shift + relu (NHWC, single batch) --
__global__ __launch_bounds__(256) void k8_conv1(const float* __restrict__ src,
        const float* __restrict__ wt, const float* __restrict__ g1,
        const float* __restrict__ b1, float* __restrict__ dst) {
    __shared__ float smem[180*65];
    int x0 = blockIdx.x*16, y0 = blockIdx.y*8, b = blockIdx.z;
    int t = threadIdx.x;
    const float* sp = src + (size_t)b*HWD*64;
    for (int i=t; i<2880; i+=256) {
        int cell = i >> 4, c4 = i & 15;
        int gy = y0 - 1 + cell/18, gx = x0 - 1 + cell%18;
        float4 v = make_float4(0.f,0.f,0.f,0.f);
        if (gy >= 0 && gy < OBJ && gx >= 0 && gx < OBJ)
            v = *(const float4*)(sp + ((size_t)gy*OBJ + gx)*64 + c4*4);
        float* d = &smem[cell*65 + c4*4];
        d[0]=v.x; d[1]=v.y; d[2]=v.z; d[3]=v.w;
    }
    __syncthreads();
    int lane = t & 63, ob = (t >> 6)*16;
    int py = lane >> 3, px = lane & 7;
    float accA[16], accB[16];
#pragma unroll
    for (int i=0; i<16; ++i) { accA[i]=0.f; accB[i]=0.f; }
#pragma unroll
    for (int dy=0; dy<3; ++dy)
#pragma unroll
    for (int dx=0; dx<3; ++dx) {
        int ca = (py+dy)*18 + (px+dx);
        const float* wp = wt + (dy*3+dx)*4096 + ob;
        for (int c=0; c<64; ++c) {
            float ia = smem[ca*65 + c];
            float ib = smem[(ca+8)*65 + c];
            const float* wr = wp + c*64;
#pragma unroll
            for (int oo=0; oo<16; ++oo) {
                float wv = wr[oo];
                accA[oo] = fmaf(ia, wv, accA[oo]);
                accB[oo] = fmaf(ib, wv, accB[oo]);
            }
        }
    }
    size_t baseA = ((size_t)b*HWD + (size_t)(y0+py)*OBJ + (x0+px))*64 + ob;
    float* dA = dst + baseA;
    float* dB = dA + 8*64;
#pragma unroll
    for (int q=0; q<4; ++q) {
        float4 va, vb;
        float* pa = (float*)&va; float* pb = (float*)&vb;
#pragma unroll
        for (int j=0; j<4; ++j) {
            int oo = q*4 + j;
            pa[j] = fmaxf(fmaf(accA[oo], g1[ob+oo], b1[ob+oo]), 0.f);
            pb[j] = fmaxf(fmaf(accB[oo], g1[ob+oo], b1[ob+oo]), 0.f);
        }
        ((float4*)dA)[q] = va;
        ((float4*)dB)[q] = vb;
    }
}

// ---------------- K9: conv3x3 + bn + residual-relu + blkout + img head ---
__global__ __launch_bounds__(256) void k9_conv2(const float* __restrict__ h1,
        const float* __restrict__ wt, const float* __restrict__ g2,
        const float* __restrict__ b2, const float* __restrict__ res,
        const float* __restrict__ wbk, const float* __restrict__ bbk,
        const float* __restrict__ wim, const float* __restrict__ bim,
        float* __restrict__ out) {
    __shared__ float smem[12480];
    int x0 = blockIdx.x*16, y0 = blockIdx.y*8, b = blockIdx.z;
    int t = threadIdx.x;
    const float* sp = h1 + (size_t)b*HWD*64;
    for (int i=t; i<2880; i+=256) {
        int cell = i >> 4, c4 = i & 15;
        int gy = y0 - 1 + cell/18, gx = x0 - 1 + cell%18;
        float4 v = make_float4(0.f,0.f,0.f,0.f);
        if (gy >= 0 && gy < OBJ && gx >= 0 && gx < OBJ)
            v = *(const float4*)(sp + ((size_t)gy*OBJ + gx)*64 + c4*4);
        float* d = &smem[cell*65 + c4*4];
        d[0]=v.x; d[1]=v.y; d[2]=v.z; d[3]=v.w;
    }
    __syncthreads();
    int lane = t & 63, ob = (t >> 6)*16;
    int py = lane >> 3, px = lane & 7;
    float accA[16], accB[16];
#pragma unroll
    for (int i=0; i<16; ++i) { accA[i]=0.f; accB[i]=0.f; }
#pragma unroll
    for (int dy=0; dy<3; ++dy)
#pragma unroll
    for (int dx=0; dx<3; ++dx) {
        int ca = (py+dy)*18 + (px+dx);
        const float* wp = wt + (dy*3+dx)*4096 + ob;
        for (int c=0; c<64; ++c) {
            float ia = smem[ca*65 + c];
            float ib = smem[(ca+8)*65 + c];
            const float* wr = wp + c*64;
#pragma unroll
            for (int oo=0; oo<16; ++oo) {
                float wv = wr[oo];
                accA[oo] = fmaf(ia, wv, accA[oo]);
                accB[oo] = fmaf(ib, wv, accB[oo]);
            }
        }
    }
    size_t baseA = ((size_t)b*HWD + (size_t)(y0+py)*OBJ + (x0+px))*64 + ob;
    const float4* rA = (const float4*)(res + baseA);
    const float4* rB = (const float4*)(res + baseA + 8*64);
#pragma unroll
    for (int q=0; q<4; ++q) {
        float4 va = rA[q], vb = rB[q];
        const float* pa = (const float*)&va; const float* pb = (const float*)&vb;
#pragma unroll
        for (int j=0; j<4; ++j) {
            int oo = q*4 + j;
            accA[oo] = fmaxf(fmaf(accA[oo], g2[ob+oo], b2[ob+oo]) + pa[j], 0.f);
            accB[oo] = fmaxf(fmaf(accB[oo], g2[ob+oo], b2[ob+oo]) + pb[j], 0.f);
        }
    }
    __syncthreads();
    for (int i=t; i<4096; i+=256) smem[8320 + (i&63)*64 + (i>>6)] = wbk[i];

    const float MEAN[3] = {0.485f, 0.456f, 0.406f};
    const float STDV[3] = {0.229f, 0.224f, 0.225f};
    int pixid = py*8 + px;
    float* treg = smem;
    float* ureg = smem + 4160;
    const float* wbkT = smem + 8320;
#pragma unroll
    for (int h=0; h<2; ++h) {
#pragma unroll
        for (int oo=0; oo<16; ++oo)
            treg[pixid*65 + ob + oo] = (h == 0) ? accA[oo] : accB[oo];
        __syncthreads();
        {
            int pix = t & 63, grp = t >> 6;
            float u[16];
#pragma unroll
            for (int oo=0; oo<16; ++oo) u[oo] = bbk[grp*16 + oo];
            for (int c=0; c<64; ++c) {
                float tv = treg[pix*65 + c];
                const float* wr = wbkT + c*64 + grp*16;
#pragma unroll
                for (int oo=0; oo<16; ++oo) u[oo] = fmaf(tv, wr[oo], u[oo]);
            }
#pragma unroll
            for (int oo=0; oo<16; ++oo) ureg[pix*65 + grp*16 + oo] = u[oo];
        }
        __syncthreads();
        if (t < 192) {
            int o = t >> 6, pix = t & 63;
            float s = bim[o];
            for (int c=0; c<64; ++c) s = fmaf(wim[o*64 + c], ureg[pix*65 + c], s);
            float sig = 1.f / (1.f + expf(-s));
            float v = (sig - MEAN[o]) / STDV[o];
            int ppy = pix >> 3, ppx = pix & 7;
            out[((size_t)(b*3 + o))*HWD + (size_t)(y0+ppy)*OBJ + x0 + h*8 + ppx] = v;
        }
        __syncthreads();
    }
}

// ---------------- launch ----------------
extern "C" void kernel_launch(void* const* d_in, const int* in_sizes, int n_in,
                              void* d_out, int out_size, void* d_ws, size_t ws_size,
                              hipStream_t stream) {
    const float* pc      = (const float*)d_in[0];
    const float* w_in    = (const float*)d_in[1];
    const float* b_in    = (const float*)d_in[2];
    const float* w_graph = (const float*)d_in[3];
    const float* gn_g    = (const float*)d_in[4];
    const float* gn_b    = (const float*)d_in[5];
    const float* w_proj  = (const float*)d_in[6];
    const float* b_proj  = (const float*)d_in[7];
    const float* bb_w1   = (const float*)d_in[8];
    const float* bb_g1   = (const float*)d_in[9];
    const float* bb_b1   = (const float*)d_in[10];
    const float* bb_w2   = (const float*)d_in[11];
    const float* bb_g2   = (const float*)d_in[12];
    const float* bb_b2   = (const float*)d_in[13];
    const float* w_blkout= (const float*)d_in[14];
    const float* b_blkout= (const float*)d_in[15];
    const float* w_img   = (const float*)d_in[16];
    const float* b_img   = (const float*)d_in[17];

    float* ws     = (float*)d_ws;
    float* res_b  = ws + RES_OFF;
    float* h1_b   = ws + H1_OFF;
    float* f      = ws + F_OFF;
    float* f0     = ws + F0_OFF;
    float* bparam = ws + BP_OFF;
    float* gsum   = ws + GS_OFF;
    float* gmu    = ws + GM_OFF;
    float* wt1    = ws + WT1_OFF;
    float* wt2    = ws + WT2_OFF;
    int*   lin    = (int*)(ws + INT_OFF);
    int*   nidx   = lin + (size_t)BB*NN*9;
    float* out    = (float*)d_out;

    hipMemsetAsync(gsum, 0, 64*sizeof(float), stream);

    k0_wt<<<144, 256, 0, stream>>>(bb_w1, wt1);
    k0_wt<<<144, 256, 0, stream>>>(bb_w2, wt2);
    k1_params<<<BB, 256, 0, stream>>>(pc, bparam);
    k2_lin<<<(BB*NN)/256, 256, 0, stream>>>(pc, bparam, lin);
    k3_f0<<<(BB*NN*8)/256, 256, 0, stream>>>(pc, w_in, b_in, f0);
    k4_knn<<<dim3(NN/256, BB), 256, 0, stream>>>(pc, nidx);
    k5_stats<<<(BB*NN)/4, 256, 0, stream>>>(f0, nidx, w_graph, gsum);
    k5b_finalize<<<1, 64, 0, stream>>>(gsum, gmu);
    k6_point<<<(BB*NN)/4, 256, 0, stream>>>(f0, nidx, w_graph, gmu, gn_g, gn_b,
                                            w_proj, b_proj, f);

    for (int b = 0; b < BB; ++b) {
        hipMemsetAsync(res_b, 0, RESB_SZ*sizeof(float), stream);
        k7_scatter<<<NN/4, 256, 0, stream>>>(f + (size_t)b*NN*64,
                                             lin + (size_t)b*NN*9, res_b);
        k8_conv1<<<dim3(14, 28, 1), 256, 0, stream>>>(res_b, wt1, bb_g1, bb_b1, h1_b);
        k9_conv2<<<dim3(14, 28, 1), 256, 0, stream>>>(h1_b, wt2, bb_g2, bb_b2, res_b,
                                                      w_blkout, b_blkout, w_img, b_img,
                                                      out + (size_t)b*3*HWD);
    }
}

// Round 12
// 2165.998 us; speedup vs baseline: 1.4148x; 1.4148x over previous
//
#include <hip/hip_runtime.h>
#include <math.h>

#define BB 8
#define NN 2048
#define KNNK 8
#define SEG 4
#define SEGN (NN/SEG)
#define OBJ 224
#define HWD (OBJ*OBJ)

// ---------------- workspace layout (float units) ----------------
// Full-batch layout (~212 MB). R1-R5 bit-identical results across the
// 211MB->32MB restructure prove ws_size >= this footprint (no corruption).
constexpr size_t RES_SZ  = (size_t)BB*HWD*64;     // 25,690,112 floats
constexpr size_t F_SZ    = (size_t)BB*NN*64;
constexpr size_t F0_SZ   = (size_t)BB*NN*8;
constexpr size_t RES_OFF = 0;
constexpr size_t H1_OFF  = RES_SZ;                // also aliases KNN partials (pre-conv)
constexpr size_t F_OFF   = 2*RES_SZ;
constexpr size_t F0_OFF  = F_OFF + F_SZ;
constexpr size_t BP_OFF  = F0_OFF + F0_SZ;        // 128 floats: per-batch params
constexpr size_t GS_OFF  = BP_OFF + 128;          // 64 floats: group sum/sumsq
constexpr size_t GM_OFF  = GS_OFF + 64;           // 64 floats: mu/rsig
constexpr size_t WT1_OFF = GM_OFF + 64;           // 36864 transposed conv1 w
constexpr size_t WT2_OFF = WT1_OFF + 36864;       // 36864 transposed conv2 w
constexpr size_t INT_OFF = WT2_OFF + 36864;       // ints: lin[B*N*9], nidx[B*N*8]

// ---------------- K0: transpose conv weights [O][C][3][3] -> [k][C][O] ----
__global__ void k0_wt(const float* __restrict__ w, float* __restrict__ wt) {
    int i = blockIdx.x*256 + threadIdx.x;
    if (i >= 64*64*9) return;
    int o = i/576, c = (i/9)%64, kk = i%9;
    wt[(size_t)(kk*64 + c)*64 + o] = w[i];
}

// ---------------- K1: per-batch grid params — fast-math (arcp) f32 -------
// FROZEN (R11 pass): reference = XLA fast-math; broadcast divide x/grid is
// compiled as x * fl(1/grid) (arcp, reciprocal hoisted via one IEEE div).
__global__ void k1_params(const float* __restrict__ pc, float* __restrict__ bparam) {
    __shared__ float r0[256], r1[256], r2[256], r3[256];
    __shared__ float sh[4];
    int b = blockIdx.x, t = threadIdx.x;
    const float* p = pc + (size_t)b*NN*3;
    float mnx=1e30f, mxx=-1e30f, mny=1e30f, mxy=-1e30f;
    for (int n=t; n<NN; n+=256) {
        float x=p[3*n], y=p[3*n+1];
        mnx=fminf(mnx,x); mxx=fmaxf(mxx,x); mny=fminf(mny,y); mxy=fmaxf(mxy,y);
    }
    r0[t]=mnx; r1[t]=mxx; r2[t]=mny; r3[t]=mxy;
    __syncthreads();
    for (int s=128; s>0; s>>=1) {
        if (t<s) { r0[t]=fminf(r0[t],r0[t+s]); r1[t]=fmaxf(r1[t],r1[t+s]);
                   r2[t]=fminf(r2[t],r2[t+s]); r3[t]=fmaxf(r3[t],r3[t+s]); }
        __syncthreads();
    }
    if (t==0) {
        float rx = __fsub_rn(r1[0], r0[0]);
        float ry = __fsub_rn(r3[0], r2[0]);
        sh[0]=r0[0]; sh[1]=r2[0];
        float c221 = __fdiv_rn(1.0f, (float)(OBJ-3));
        float grid = __fmul_rn(fmaxf(rx,ry), c221);
        sh[2] = grid;
        sh[3] = __fdiv_rn(1.0f, grid);               // hoisted reciprocal (arcp)
    }
    __syncthreads();
    float minx=sh[0], miny=sh[1], rgrid=sh[3];
    mnx=1e30f; mxx=-1e30f; mny=1e30f; mxy=-1e30f;
    for (int n=t; n<NN; n+=256) {
        float ix = floorf(__fmul_rn(__fsub_rn(p[3*n],   minx), rgrid));
        float iy = floorf(__fmul_rn(__fsub_rn(p[3*n+1], miny), rgrid));
        mnx=fminf(mnx,ix); mxx=fmaxf(mxx,ix); mny=fminf(mny,iy); mxy=fmaxf(mxy,iy);
    }
    __syncthreads();
    r0[t]=mnx; r1[t]=mxx; r2[t]=mny; r3[t]=mxy;
    __syncthreads();
    for (int s=128; s>0; s>>=1) {
        if (t<s) { r0[t]=fminf(r0[t],r0[t+s]); r1[t]=fmaxf(r1[t],r1[t+s]);
                   r2[t]=fminf(r2[t],r2[t+s]); r3[t]=fmaxf(r3[t],r3[t+s]); }
        __syncthreads();
    }
    if (t==0) {
        float cx = floorf((r1[0] + 2.0f + r0[0]) * 0.5f);
        float cy = floorf((r3[0] + 2.0f + r2[0]) * 0.5f);
        bparam[b*8+0]=minx; bparam[b*8+1]=miny; bparam[b*8+2]=sh[3];  // rgrid
        bparam[b*8+3]=112.0f - cx - 1.0f;
        bparam[b*8+4]=112.0f - cy - 1.0f;
    }
}

// ---------------- K2: linear grid indices — FROZEN (arcp) ----------------
__global__ void k2_lin(const float* __restrict__ pc, const float* __restrict__ bparam,
                       int* __restrict__ lin) {
    int i = blockIdx.x*256 + threadIdx.x;     // b*N+n
    if (i >= BB*NN) return;
    int b = i / NN;
    float x = pc[(size_t)i*3], y = pc[(size_t)i*3+1];
    float minx=bparam[b*8], miny=bparam[b*8+1], rgrid=bparam[b*8+2];
    float offx=bparam[b*8+3], offy=bparam[b*8+4];
    float ix = floorf(__fmul_rn(__fsub_rn(x, minx), rgrid));
    float iy = floorf(__fmul_rn(__fsub_rn(y, miny), rgrid));
    const float o9x[9] = {-1,-1,-1, 0,0,0, 1,1,1};
    const float o9y[9] = {-1, 0, 1,-1,0,1,-1,0,1};
#pragma unroll
    for (int j=0; j<9; ++j) {
        float dx = ix + o9x[j] + 1.0f + offx;
        float dy = iy + o9y[j] + 1.0f + offy;
        dx += (dx < 0.f ? 1.f : 0.f) - (dx > 223.f ? 1.f : 0.f);
        dy += (dy < 0.f ? 1.f : 0.f) - (dy > 223.f ? 1.f : 0.f);
        lin[(size_t)i*9 + j] = (int)(dx*224.f + dy);
    }
}

// ---------------- K3: f0 = pc @ w_in^T + b_in ----------------
__global__ void k3_f0(const float* __restrict__ pc, const float* __restrict__ w_in,
                      const float* __restrict__ b_in, float* __restrict__ f0) {
    int i = blockIdx.x*256 + threadIdx.x;
    if (i >= BB*NN*8) return;
    int o = i & 7; int bn = i >> 3;
    float x=pc[(size_t)bn*3], y=pc[(size_t)bn*3+1], z=pc[(size_t)bn*3+2];
    f0[i] = x*w_in[o*3] + y*w_in[o*3+1] + z*w_in[o*3+2] + b_in[o];
}

// ---------------- K4: segmented KNN — 4x parallelism + 8x ILP ------------
// R11 PMC: monolithic k4 was 470us at 2.8% occupancy, VALUBusy 11% —
// latency-bound serial loop, 64 blocks. Split the candidate range into SEG=4
// segments (256 blocks) and unroll by 8 so LDS loads pipeline. Distances are
// bit-identical per candidate; partial lists are (d, idx)-stable; the merge
// below is lexicographic (d, idx), exactly reproducing the single-pass
// stable insertion (strict <, lower idx on ties).
__global__ __launch_bounds__(256) void k4_knn(const float* __restrict__ pc,
                                              float* __restrict__ pd,
                                              int* __restrict__ pi) {
    __shared__ float4 pts[SEGN];
    int b = blockIdx.y, t = threadIdx.x, seg = blockIdx.z;
    const float* p = pc + (size_t)b*NN*3;
    int m0 = seg*SEGN;
    for (int m=t; m<SEGN; m+=256) {
        int mm = m0 + m;
        float x=p[3*mm], y=p[3*mm+1], z=p[3*mm+2];
        float sq = __fadd_rn(__fadd_rn(__fmul_rn(x,x), __fmul_rn(y,y)), __fmul_rn(z,z));
        pts[m] = make_float4(x, y, z, sq);
    }
    __syncthreads();
    int n = blockIdx.x*256 + t;
    float mx = p[3*n], my = p[3*n+1], mz = p[3*n+2];
    float msq = __fadd_rn(__fadd_rn(__fmul_rn(mx,mx), __fmul_rn(my,my)), __fmul_rn(mz,mz));
    float bd[KNNK]; int bi[KNNK];
#pragma unroll
    for (int j=0; j<KNNK; ++j) { bd[j]=1e30f; bi[j]=0; }
#pragma unroll 8
    for (int m=0; m<SEGN; ++m) {
        float4 q = pts[m];
        float dot = __fadd_rn(__fadd_rn(__fmul_rn(mz,q.z), __fmul_rn(my,q.y)),
                              __fmul_rn(mx,q.x));
        float d = __fsub_rn(__fadd_rn(msq, q.w), __fmul_rn(2.0f, dot));
        if (d < bd[KNNK-1]) {
            float v=d; int vi=m0+m;
#pragma unroll
            for (int j=0; j<KNNK; ++j) {
                if (v < bd[j]) { float tv=bd[j]; int ti=bi[j]; bd[j]=v; bi[j]=vi; v=tv; vi=ti; }
            }
        }
    }
    size_t base = (((size_t)b*NN + n)*SEG + seg)*KNNK;
#pragma unroll
    for (int j=0; j<KNNK; ++j) { pd[base+j] = bd[j]; pi[base+j] = bi[j]; }
}

// ---------------- K4b: merge 4 sorted partial top-8 lists ----------------
__global__ void k4b_merge(const float* __restrict__ pd, const int* __restrict__ pi,
                          int* __restrict__ nidx) {
    int i = blockIdx.x*256 + threadIdx.x;     // b*N+n
    if (i >= BB*NN) return;
    float d[SEG][KNNK]; int id[SEG][KNNK]; int ptr[SEG];
    size_t base = (size_t)i*SEG*KNNK;
#pragma unroll
    for (int s=0; s<SEG; ++s) {
        ptr[s]=0;
#pragma unroll
        for (int j=0; j<KNNK; ++j) { d[s][j]=pd[base+s*KNNK+j]; id[s][j]=pi[base+s*KNNK+j]; }
    }
#pragma unroll
    for (int j=0; j<KNNK; ++j) {
        int best=0; float bdv=1e30f; int bidx=0x7fffffff;
#pragma unroll
        for (int s=0; s<SEG; ++s) {
            float dv = (ptr[s]<KNNK) ? d[s][ptr[s]] : 1e30f;
            int   iv = (ptr[s]<KNNK) ? id[s][ptr[s]] : 0x7fffffff;
            if (dv < bdv || (dv == bdv && iv < bidx)) { best=s; bdv=dv; bidx=iv; }
        }
        nidx[(size_t)i*KNNK + j] = bidx;
        ptr[best]++;
    }
}

// ---------------- feat builder (shared by K5/K6) ----------------
__device__ __forceinline__ void build_feat(int t, int b, int n0,
        const float* __restrict__ f0, const int* __restrict__ nidx,
        float feat[4][8][16]) {
    int pt = t >> 6, k = (t >> 3) & 7, c = t & 7;
    int n  = n0 + pt;
    int nb = nidx[((size_t)b*NN + n)*8 + k];
    float f0c = f0[((size_t)b*NN + n)*8 + c];
    float fnc = f0[((size_t)b*NN + nb)*8 + c];
    feat[pt][k][c]   = fnc - f0c;
    feat[pt][k][c+8] = f0c;
}

// ---------------- K5: GroupNorm stats pass ----------------
__global__ __launch_bounds__(256) void k5_stats(const float* __restrict__ f0,
        const int* __restrict__ nidx, const float* __restrict__ w_graph,
        float* __restrict__ gsum) {
    __shared__ float wgT[16*64];
    __shared__ float feat[4][8][16];
    __shared__ float part[4][4][2];
    int t = threadIdx.x;
    for (int i=t; i<1024; i+=256) wgT[(i&15)*64 + (i>>4)] = w_graph[i];
    int blk = blockIdx.x;
    int b = blk >> 9, n0 = (blk & 511)*4;
    build_feat(t, b, n0, f0, nidx, feat);
    __syncthreads();
    int pt = t >> 6, o = t & 63;
    float s = 0.f, s2 = 0.f;
#pragma unroll
    for (int k=0; k<8; ++k) {
        float g = 0.f;
#pragma unroll
        for (int c=0; c<16; ++c) g = fmaf(feat[pt][k][c], wgT[c*64+o], g);
        s += g; s2 += g*g;
    }
#pragma unroll
    for (int off=8; off; off>>=1) {
        s  += __shfl_down(s,  off, 16);
        s2 += __shfl_down(s2, off, 16);
    }
    if ((o & 15) == 0) { part[pt][o>>4][0] = s; part[pt][o>>4][1] = s2; }
    __syncthreads();
    if (t < 8) {
        int grp = t >> 1, which = t & 1;
        float v = part[0][grp][which] + part[1][grp][which]
                + part[2][grp][which] + part[3][grp][which];
        atomicAdd(&gsum[(b*4+grp)*2 + which], v);
    }
}

__global__ void k5b_finalize(const float* __restrict__ gsum, float* __restrict__ gmu) {
    int t = threadIdx.x;
    if (t < 32) {
        const float cnt = (float)(NN*KNNK*16);
        float mu = gsum[t*2] / cnt;
        float var = gsum[t*2+1] / cnt - mu*mu;
        gmu[t*2]   = mu;
        gmu[t*2+1] = 1.0f / sqrtf(var + 1e-5f);
    }
}

// ---------------- K6: normalize + leaky + max_k + proj ----------------
__global__ __launch_bounds__(256) void k6_point(const float* __restrict__ f0,
        const int* __restrict__ nidx, const float* __restrict__ w_graph,
        const float* __restrict__ gmu, const float* __restrict__ gn_g,
        const float* __restrict__ gn_b, const float* __restrict__ w_proj,
        const float* __restrict__ b_proj, float* __restrict__ f) {
    __shared__ float wgT[16*64];
    __shared__ float wpT[64*64];
    __shared__ float feat[4][8][16];
    __shared__ float gmax_s[4][64];
    int t = threadIdx.x;
    for (int i=t; i<1024; i+=256) wgT[(i&15)*64 + (i>>4)] = w_graph[i];
    for (int i=t; i<4096; i+=256) wpT[(i&63)*64 + (i>>6)] = w_proj[i];
    int blk = blockIdx.x;
    int b = blk >> 9, n0 = (blk & 511)*4;
    build_feat(t, b, n0, f0, nidx, feat);
    __syncthreads();
    int pt = t >> 6, o = t & 63;
    int grp = o >> 4;
    float mu = gmu[(b*4+grp)*2], rsig = gmu[(b*4+grp)*2+1];
    float ga = gn_g[o], be = gn_b[o];
    float gm = -1e30f;
#pragma unroll
    for (int k=0; k<8; ++k) {
        float g = 0.f;
#pragma unroll
        for (int c=0; c<16; ++c) g = fmaf(feat[pt][k][c], wgT[c*64+o], g);
        float v = (g - mu)*rsig*ga + be;
        v = (v >= 0.f) ? v : 0.2f*v;
        gm = fmaxf(gm, v);
    }
    gmax_s[pt][o] = gm;
    __syncthreads();
    float acc = b_proj[o];
#pragma unroll
    for (int c=0; c<64; ++c) acc = fmaf(gmax_s[pt][c], wpT[c*64+o], acc);
    f[((size_t)b*NN + n0 + pt)*64 + o] = acc;
}

// ---------------- K7: scatter-sum onto NHWC grid (all batches) -----------
__global__ __launch_bounds__(256) void k7_scatter(const float* __restrict__ f,
        const int* __restrict__ lin, float* __restrict__ res) {
    int blk = blockIdx.x, t = threadIdx.x;
    int b = blk >> 9;
    int n = (blk & 511)*4 + (t >> 6);
    int o = t & 63;
    size_t bn = (size_t)b*NN + n;
    float v = f[bn*64 + o];
#pragma unroll
    for (int j=0; j<9; ++j) {
        int cell = lin[bn*9 + j];
        if (cell >= 0 && cell < HWD)
            atomicAdd(&res[((size_t)b*HWD + cell)*64 + o], v);
    }
}

// ---------------- K8: conv3x3 + scale/shift + relu (NHWC, batch-par) -----
__global__ __launch_bounds__(256) void k8_conv1(const float* __restrict__ src,
        const float* __restrict__ wt, const float* __restrict__ g1,
        const float* __restrict__ b1, float* __restrict__ dst) {
    __shared__ float smem[180*65];
    int x0 = blockIdx.x*16, y0 = blockIdx.y*8, b = blockIdx.z;
    int t = threadIdx.x;
    const float* sp = src + (size_t)b*HWD*64;
    for (int i=t; i<2880; i+=256) {
        int cell = i >> 4, c4 = i & 15;
        int gy = y0 - 1 + cell/18, gx = x0 - 1 + cell%18;
        float4 v = make_float4(0.f,0.f,0.f,0.f);
        if (gy >= 0 && gy < OBJ && gx >= 0 && gx < OBJ)
            v = *(const float4*)(sp + ((size_t)gy*OBJ + gx)*64 + c4*4);
        float* d = &smem[cell*65 + c4*4];
        d[0]=v.x; d[1]=v.y; d[2]=v.z; d[3]=v.w;
    }
    __syncthreads();
    int lane = t & 63, ob = (t >> 6)*16;
    int py = lane >> 3, px = lane & 7;
    float accA[16], accB[16];
#pragma unroll
    for (int i=0; i<16; ++i) { accA[i]=0.f; accB[i]=0.f; }
#pragma unroll
    for (int dy=0; dy<3; ++dy)
#pragma unroll
    for (int dx=0; dx<3; ++dx) {
        int ca = (py+dy)*18 + (px+dx);
        const float* wp = wt + (dy*3+dx)*4096 + ob;
        for (int c=0; c<64; ++c) {
            float ia = smem[ca*65 + c];
            float ib = smem[(ca+8)*65 + c];
            const float* wr = wp + c*64;
#pragma unroll
            for (int oo=0; oo<16; ++oo) {
                float wv = wr[oo];
                accA[oo] = fmaf(ia, wv, accA[oo]);
                accB[oo] = fmaf(ib, wv, accB[oo]);
            }
        }
    }
    size_t baseA = ((size_t)b*HWD + (size_t)(y0+py)*OBJ + (x0+px))*64 + ob;
    float* dA = dst + baseA;
    float* dB = dA + 8*64;
#pragma unroll
    for (int q=0; q<4; ++q) {
        float4 va, vb;
        float* pa = (float*)&va; float* pb = (float*)&vb;
#pragma unroll
        for (int j=0; j<4; ++j) {
            int oo = q*4 + j;
            pa[j] = fmaxf(fmaf(accA[oo], g1[ob+oo], b1[ob+oo]), 0.f);
            pb[j] = fmaxf(fmaf(accB[oo], g1[ob+oo], b1[ob+oo]), 0.f);
        }
        ((float4*)dA)[q] = va;
        ((float4*)dB)[q] = vb;
    }
}

// ---------------- K9: conv3x3 + bn + residual-relu + blkout + img head ---
__global__ __launch_bounds__(256) void k9_conv2(const float* __restrict__ h1,
        const float* __restrict__ wt, const float* __restrict__ g2,
        const float* __restrict__ b2, const float* __restrict__ res,
        const float* __restrict__ wbk, const float* __restrict__ bbk,
        const float* __restrict__ wim, const float* __restrict__ bim,
        float* __restrict__ out) {
    __shared__ float smem[12480];
    int x0 = blockIdx.x*16, y0 = blockIdx.y*8, b = blockIdx.z;
    int t = threadIdx.x;
    const float* sp = h1 + (size_t)b*HWD*64;
    for (int i=t; i<2880; i+=256) {
        int cell = i >> 4, c4 = i & 15;
        int gy = y0 - 1 + cell/18, gx = x0 - 1 + cell%18;
        float4 v = make_float4(0.f,0.f,0.f,0.f);
        if (gy >= 0 && gy < OBJ && gx >= 0 && gx < OBJ)
            v = *(const float4*)(sp + ((size_t)gy*OBJ + gx)*64 + c4*4);
        float* d = &smem[cell*65 + c4*4];
        d[0]=v.x; d[1]=v.y; d[2]=v.z; d[3]=v.w;
    }
    __syncthreads();
    int lane = t & 63, ob = (t >> 6)*16;
    int py = lane >> 3, px = lane & 7;
    float accA[16], accB[16];
#pragma unroll
    for (int i=0; i<16; ++i) { accA[i]=0.f; accB[i]=0.f; }
#pragma unroll
    for (int dy=0; dy<3; ++dy)
#pragma unroll
    for (int dx=0; dx<3; ++dx) {
        int ca = (py+dy)*18 + (px+dx);
        const float* wp = wt + (dy*3+dx)*4096 + ob;
        for (int c=0; c<64; ++c) {
            float ia = smem[ca*65 + c];
            float ib = smem[(ca+8)*65 + c];
            const float* wr = wp + c*64;
#pragma unroll
            for (int oo=0; oo<16; ++oo) {
                float wv = wr[oo];
                accA[oo] = fmaf(ia, wv, accA[oo]);
                accB[oo] = fmaf(ib, wv, accB[oo]);
            }
        }
    }
    size_t baseA = ((size_t)b*HWD + (size_t)(y0+py)*OBJ + (x0+px))*64 + ob;
    const float4* rA = (const float4*)(res + baseA);
    const float4* rB = (const float4*)(res + baseA + 8*64);
#pragma unroll
    for (int q=0; q<4; ++q) {
        float4 va = rA[q], vb = rB[q];
        const float* pa = (const float*)&va; const float* pb = (const float*)&vb;
#pragma unroll
        for (int j=0; j<4; ++j) {
            int oo = q*4 + j;
            accA[oo] = fmaxf(fmaf(accA[oo], g2[ob+oo], b2[ob+oo]) + pa[j], 0.f);
            accB[oo] = fmaxf(fmaf(accB[oo], g2[ob+oo], b2[ob+oo]) + pb[j], 0.f);
        }
    }
    __syncthreads();
    for (int i=t; i<4096; i+=256) smem[8320 + (i&63)*64 + (i>>6)] = wbk[i];

    const float MEAN[3] = {0.485f, 0.456f, 0.406f};
    const float STDV[3] = {0.229f, 0.224f, 0.225f};
    int pixid = py*8 + px;
    float* treg = smem;
    float* ureg = smem + 4160;
    const float* wbkT = smem + 8320;
#pragma unroll
    for (int h=0; h<2; ++h) {
#pragma unroll
        for (int oo=0; oo<16; ++oo)
            treg[pixid*65 + ob + oo] = (h == 0) ? accA[oo] : accB[oo];
        __syncthreads();
        {
            int pix = t & 63, grp = t >> 6;
            float u[16];
#pragma unroll
            for (int oo=0; oo<16; ++oo) u[oo] = bbk[grp*16 + oo];
            for (int c=0; c<64; ++c) {
                float tv = treg[pix*65 + c];
                const float* wr = wbkT + c*64 + grp*16;
#pragma unroll
                for (int oo=0; oo<16; ++oo) u[oo] = fmaf(tv, wr[oo], u[oo]);
            }
#pragma unroll
            for (int oo=0; oo<16; ++oo) ureg[pix*65 + grp*16 + oo] = u[oo];
        }
        __syncthreads();
        if (t < 192) {
            int o = t >> 6, pix = t & 63;
            float s = bim[o];
            for (int c=0; c<64; ++c) s = fmaf(wim[o*64 + c], ureg[pix*65 + c], s);
            float sig = 1.f / (1.f + expf(-s));
            float v = (sig - MEAN[o]) / STDV[o];
            int ppy = pix >> 3, ppx = pix & 7;
            out[((size_t)(b*3 + o))*HWD + (size_t)(y0+ppy)*OBJ + x0 + h*8 + ppx] = v;
        }
        __syncthreads();
    }
}

// ---------------- launch ----------------
extern "C" void kernel_launch(void* const* d_in, const int* in_sizes, int n_in,
                              void* d_out, int out_size, void* d_ws, size_t ws_size,
                              hipStream_t stream) {
    const float* pc      = (const float*)d_in[0];
    const float* w_in    = (const float*)d_in[1];
    const float* b_in    = (const float*)d_in[2];
    const float* w_graph = (const float*)d_in[3];
    const float* gn_g    = (const float*)d_in[4];
    const float* gn_b    = (const float*)d_in[5];
    const float* w_proj  = (const float*)d_in[6];
    const float* b_proj  = (const float*)d_in[7];
    const float* bb_w1   = (const float*)d_in[8];
    const float* bb_g1   = (const float*)d_in[9];
    const float* bb_b1   = (const float*)d_in[10];
    const float* bb_w2   = (const float*)d_in[11];
    const float* bb_g2   = (const float*)d_in[12];
    const float* bb_b2   = (const float*)d_in[13];
    const float* w_blkout= (const float*)d_in[14];
    const float* b_blkout= (const float*)d_in[15];
    const float* w_img   = (const float*)d_in[16];
    const float* b_img   = (const float*)d_in[17];

    float* ws     = (float*)d_ws;
    float* res    = ws + RES_OFF;
    float* h1     = ws + H1_OFF;
    float* pd     = ws + H1_OFF;                      // KNN partials alias h1
    int*   pi     = (int*)(ws + H1_OFF + (size_t)BB*NN*SEG*KNNK);
    float* f      = ws + F_OFF;
    float* f0     = ws + F0_OFF;
    float* bparam = ws + BP_OFF;
    float* gsum   = ws + GS_OFF;
    float* gmu    = ws + GM_OFF;
    float* wt1    = ws + WT1_OFF;
    float* wt2    = ws + WT2_OFF;
    int*   lin    = (int*)(ws + INT_OFF);
    int*   nidx   = lin + (size_t)BB*NN*9;
    float* out    = (float*)d_out;

    hipMemsetAsync(res, 0, RES_SZ*sizeof(float), stream);
    hipMemsetAsync(gsum, 0, 64*sizeof(float), stream);

    k0_wt<<<144, 256, 0, stream>>>(bb_w1, wt1);
    k0_wt<<<144, 256, 0, stream>>>(bb_w2, wt2);
    k1_params<<<BB, 256, 0, stream>>>(pc, bparam);
    k2_lin<<<(BB*NN)/256, 256, 0, stream>>>(pc, bparam, lin);
    k3_f0<<<(BB*NN*8)/256, 256, 0, stream>>>(pc, w_in, b_in, f0);
    k4_knn<<<dim3(NN/256, BB, SEG), 256, 0, stream>>>(pc, pd, pi);
    k4b_merge<<<(BB*NN)/256, 256, 0, stream>>>(pd, pi, nidx);
    k5_stats<<<(BB*NN)/4, 256, 0, stream>>>(f0, nidx, w_graph, gsum);
    k5b_finalize<<<1, 64, 0, stream>>>(gsum, gmu);
    k6_point<<<(BB*NN)/4, 256, 0, stream>>>(f0, nidx, w_graph, gmu, gn_g, gn_b,
                                            w_proj, b_proj, f);
    k7_scatter<<<(BB*NN)/4, 256, 0, stream>>>(f, lin, res);
    k8_conv1<<<dim3(14, 28, BB), 256, 0, stream>>>(res, wt1, bb_g1, bb_b1, h1);
    k9_conv2<<<dim3(14, 28, BB), 256, 0, stream>>>(h1, wt2, bb_g2, bb_b2, res,
                                                   w_blkout, b_blkout, w_img, b_img, out);
}

// Round 13
// 1076.558 us; speedup vs baseline: 2.8466x; 2.0120x over previous
//
#include <hip/hip_runtime.h>
#include <math.h>

#define BB 8
#define NN 2048
#define KNNK 8
#define SEG 4
#define SEGN (NN/SEG)
#define OBJ 224
#define HWD (OBJ*OBJ)

// ---------------- workspace layout (float units) ----------------
constexpr size_t RES_SZ  = (size_t)BB*HWD*64;     // 25,690,112 floats
constexpr size_t F_SZ    = (size_t)BB*NN*64;
constexpr size_t F0_SZ   = (size_t)BB*NN*8;
constexpr size_t RES_OFF = 0;
constexpr size_t H1_OFF  = RES_SZ;                // also aliases KNN partials (pre-conv)
constexpr size_t F_OFF   = 2*RES_SZ;
constexpr size_t F0_OFF  = F_OFF + F_SZ;
constexpr size_t BP_OFF  = F0_OFF + F0_SZ;
constexpr size_t GS_OFF  = BP_OFF + 128;
constexpr size_t GM_OFF  = GS_OFF + 64;
constexpr size_t WT1_OFF = GM_OFF + 64;
constexpr size_t WT2_OFF = WT1_OFF + 36864;
constexpr size_t INT_OFF = WT2_OFF + 36864;

// ---------------- K0: transpose conv weights [O][C][3][3] -> [k][C][O] ----
__global__ void k0_wt(const float* __restrict__ w, float* __restrict__ wt) {
    int i = blockIdx.x*256 + threadIdx.x;
    if (i >= 64*64*9) return;
    int o = i/576, c = (i/9)%64, kk = i%9;
    wt[(size_t)(kk*64 + c)*64 + o] = w[i];
}

// ---------------- K1: per-batch grid params — FROZEN (arcp f32, R11) -----
__global__ void k1_params(const float* __restrict__ pc, float* __restrict__ bparam) {
    __shared__ float r0[256], r1[256], r2[256], r3[256];
    __shared__ float sh[4];
    int b = blockIdx.x, t = threadIdx.x;
    const float* p = pc + (size_t)b*NN*3;
    float mnx=1e30f, mxx=-1e30f, mny=1e30f, mxy=-1e30f;
    for (int n=t; n<NN; n+=256) {
        float x=p[3*n], y=p[3*n+1];
        mnx=fminf(mnx,x); mxx=fmaxf(mxx,x); mny=fminf(mny,y); mxy=fmaxf(mxy,y);
    }
    r0[t]=mnx; r1[t]=mxx; r2[t]=mny; r3[t]=mxy;
    __syncthreads();
    for (int s=128; s>0; s>>=1) {
        if (t<s) { r0[t]=fminf(r0[t],r0[t+s]); r1[t]=fmaxf(r1[t],r1[t+s]);
                   r2[t]=fminf(r2[t],r2[t+s]); r3[t]=fmaxf(r3[t],r3[t+s]); }
        __syncthreads();
    }
    if (t==0) {
        float rx = __fsub_rn(r1[0], r0[0]);
        float ry = __fsub_rn(r3[0], r2[0]);
        sh[0]=r0[0]; sh[1]=r2[0];
        float c221 = __fdiv_rn(1.0f, (float)(OBJ-3));
        float grid = __fmul_rn(fmaxf(rx,ry), c221);
        sh[2] = grid;
        sh[3] = __fdiv_rn(1.0f, grid);               // hoisted reciprocal (arcp)
    }
    __syncthreads();
    float minx=sh[0], miny=sh[1], rgrid=sh[3];
    mnx=1e30f; mxx=-1e30f; mny=1e30f; mxy=-1e30f;
    for (int n=t; n<NN; n+=256) {
        float ix = floorf(__fmul_rn(__fsub_rn(p[3*n],   minx), rgrid));
        float iy = floorf(__fmul_rn(__fsub_rn(p[3*n+1], miny), rgrid));
        mnx=fminf(mnx,ix); mxx=fmaxf(mxx,ix); mny=fminf(mny,iy); mxy=fmaxf(mxy,iy);
    }
    __syncthreads();
    r0[t]=mnx; r1[t]=mxx; r2[t]=mny; r3[t]=mxy;
    __syncthreads();
    for (int s=128; s>0; s>>=1) {
        if (t<s) { r0[t]=fminf(r0[t],r0[t+s]); r1[t]=fmaxf(r1[t],r1[t+s]);
                   r2[t]=fminf(r2[t],r2[t+s]); r3[t]=fmaxf(r3[t],r3[t+s]); }
        __syncthreads();
    }
    if (t==0) {
        float cx = floorf((r1[0] + 2.0f + r0[0]) * 0.5f);
        float cy = floorf((r3[0] + 2.0f + r2[0]) * 0.5f);
        bparam[b*8+0]=minx; bparam[b*8+1]=miny; bparam[b*8+2]=sh[3];
        bparam[b*8+3]=112.0f - cx - 1.0f;
        bparam[b*8+4]=112.0f - cy - 1.0f;
    }
}

// ---------------- K2: linear grid indices — FROZEN (arcp) ----------------
__global__ void k2_lin(const float* __restrict__ pc, const float* __restrict__ bparam,
                       int* __restrict__ lin) {
    int i = blockIdx.x*256 + threadIdx.x;
    if (i >= BB*NN) return;
    int b = i / NN;
    float x = pc[(size_t)i*3], y = pc[(size_t)i*3+1];
    float minx=bparam[b*8], miny=bparam[b*8+1], rgrid=bparam[b*8+2];
    float offx=bparam[b*8+3], offy=bparam[b*8+4];
    float ix = floorf(__fmul_rn(__fsub_rn(x, minx), rgrid));
    float iy = floorf(__fmul_rn(__fsub_rn(y, miny), rgrid));
    const float o9x[9] = {-1,-1,-1, 0,0,0, 1,1,1};
    const float o9y[9] = {-1, 0, 1,-1,0,1,-1,0,1};
#pragma unroll
    for (int j=0; j<9; ++j) {
        float dx = ix + o9x[j] + 1.0f + offx;
        float dy = iy + o9y[j] + 1.0f + offy;
        dx += (dx < 0.f ? 1.f : 0.f) - (dx > 223.f ? 1.f : 0.f);
        dy += (dy < 0.f ? 1.f : 0.f) - (dy > 223.f ? 1.f : 0.f);
        lin[(size_t)i*9 + j] = (int)(dx*224.f + dy);
    }
}

// ---------------- K3: f0 = pc @ w_in^T + b_in ----------------
__global__ void k3_f0(const float* __restrict__ pc, const float* __restrict__ w_in,
                      const float* __restrict__ b_in, float* __restrict__ f0) {
    int i = blockIdx.x*256 + threadIdx.x;
    if (i >= BB*NN*8) return;
    int o = i & 7; int bn = i >> 3;
    float x=pc[(size_t)bn*3], y=pc[(size_t)bn*3+1], z=pc[(size_t)bn*3+2];
    f0[i] = x*w_in[o*3] + y*w_in[o*3+1] + z*w_in[o*3+2] + b_in[o];
}

// ---------------- K4: segmented KNN (R12 WIN config) ---------------------
__global__ __launch_bounds__(256) void k4_knn(const float* __restrict__ pc,
                                              float* __restrict__ pd,
                                              int* __restrict__ pi) {
    __shared__ float4 pts[SEGN];
    int b = blockIdx.y, t = threadIdx.x, seg = blockIdx.z;
    const float* p = pc + (size_t)b*NN*3;
    int m0 = seg*SEGN;
    for (int m=t; m<SEGN; m+=256) {
        int mm = m0 + m;
        float x=p[3*mm], y=p[3*mm+1], z=p[3*mm+2];
        float sq = __fadd_rn(__fadd_rn(__fmul_rn(x,x), __fmul_rn(y,y)), __fmul_rn(z,z));
        pts[m] = make_float4(x, y, z, sq);
    }
    __syncthreads();
    int n = blockIdx.x*256 + t;
    float mx = p[3*n], my = p[3*n+1], mz = p[3*n+2];
    float msq = __fadd_rn(__fadd_rn(__fmul_rn(mx,mx), __fmul_rn(my,my)), __fmul_rn(mz,mz));
    float bd[KNNK]; int bi[KNNK];
#pragma unroll
    for (int j=0; j<KNNK; ++j) { bd[j]=1e30f; bi[j]=0; }
#pragma unroll 8
    for (int m=0; m<SEGN; ++m) {
        float4 q = pts[m];
        float dot = __fadd_rn(__fadd_rn(__fmul_rn(mz,q.z), __fmul_rn(my,q.y)),
                              __fmul_rn(mx,q.x));
        float d = __fsub_rn(__fadd_rn(msq, q.w), __fmul_rn(2.0f, dot));
        if (d < bd[KNNK-1]) {
            float v=d; int vi=m0+m;
#pragma unroll
            for (int j=0; j<KNNK; ++j) {
                if (v < bd[j]) { float tv=bd[j]; int ti=bi[j]; bd[j]=v; bi[j]=vi; v=tv; vi=ti; }
            }
        }
    }
    size_t base = (((size_t)b*NN + n)*SEG + seg)*KNNK;
#pragma unroll
    for (int j=0; j<KNNK; ++j) { pd[base+j] = bd[j]; pi[base+j] = bi[j]; }
}

// ---------------- K4b: merge 4 sorted partial top-8 lists ----------------
__global__ void k4b_merge(const float* __restrict__ pd, const int* __restrict__ pi,
                          int* __restrict__ nidx) {
    int i = blockIdx.x*256 + threadIdx.x;
    if (i >= BB*NN) return;
    float d[SEG][KNNK]; int id[SEG][KNNK]; int ptr[SEG];
    size_t base = (size_t)i*SEG*KNNK;
#pragma unroll
    for (int s=0; s<SEG; ++s) {
        ptr[s]=0;
#pragma unroll
        for (int j=0; j<KNNK; ++j) { d[s][j]=pd[base+s*KNNK+j]; id[s][j]=pi[base+s*KNNK+j]; }
    }
#pragma unroll
    for (int j=0; j<KNNK; ++j) {
        int best=0; float bdv=1e30f; int bidx=0x7fffffff;
#pragma unroll
        for (int s=0; s<SEG; ++s) {
            float dv = (ptr[s]<KNNK) ? d[s][ptr[s]] : 1e30f;
            int   iv = (ptr[s]<KNNK) ? id[s][ptr[s]] : 0x7fffffff;
            if (dv < bdv || (dv == bdv && iv < bidx)) { best=s; bdv=dv; bidx=iv; }
        }
        nidx[(size_t)i*KNNK + j] = bidx;
        ptr[best]++;
    }
}

// ---------------- feat builder (shared by K5/K6) ----------------
__device__ __forceinline__ void build_feat(int t, int b, int n0,
        const float* __restrict__ f0, const int* __restrict__ nidx,
        float feat[4][8][16]) {
    int pt = t >> 6, k = (t >> 3) & 7, c = t & 7;
    int n  = n0 + pt;
    int nb = nidx[((size_t)b*NN + n)*8 + k];
    float f0c = f0[((size_t)b*NN + n)*8 + c];
    float fnc = f0[((size_t)b*NN + nb)*8 + c];
    feat[pt][k][c]   = fnc - f0c;
    feat[pt][k][c+8] = f0c;
}

// ---------------- K5: GroupNorm stats pass ----------------
__global__ __launch_bounds__(256) void k5_stats(const float* __restrict__ f0,
        const int* __restrict__ nidx, const float* __restrict__ w_graph,
        float* __restrict__ gsum) {
    __shared__ float wgT[16*64];
    __shared__ float feat[4][8][16];
    __shared__ float part[4][4][2];
    int t = threadIdx.x;
    for (int i=t; i<1024; i+=256) wgT[(i&15)*64 + (i>>4)] = w_graph[i];
    int blk = blockIdx.x;
    int b = blk >> 9, n0 = (blk & 511)*4;
    build_feat(t, b, n0, f0, nidx, feat);
    __syncthreads();
    int pt = t >> 6, o = t & 63;
    float s = 0.f, s2 = 0.f;
#pragma unroll
    for (int k=0; k<8; ++k) {
        float g = 0.f;
#pragma unroll
        for (int c=0; c<16; ++c) g = fmaf(feat[pt][k][c], wgT[c*64+o], g);
        s += g; s2 += g*g;
    }
#pragma unroll
    for (int off=8; off; off>>=1) {
        s  += __shfl_down(s,  off, 16);
        s2 += __shfl_down(s2, off, 16);
    }
    if ((o & 15) == 0) { part[pt][o>>4][0] = s; part[pt][o>>4][1] = s2; }
    __syncthreads();
    if (t < 8) {
        int grp = t >> 1, which = t & 1;
        float v = part[0][grp][which] + part[1][grp][which]
                + part[2][grp][which] + part[3][grp][which];
        atomicAdd(&gsum[(b*4+grp)*2 + which], v);
    }
}

__global__ void k5b_finalize(const float* __restrict__ gsum, float* __restrict__ gmu) {
    int t = threadIdx.x;
    if (t < 32) {
        const float cnt = (float)(NN*KNNK*16);
        float mu = gsum[t*2] / cnt;
        float var = gsum[t*2+1] / cnt - mu*mu;
        gmu[t*2]   = mu;
        gmu[t*2+1] = 1.0f / sqrtf(var + 1e-5f);
    }
}

// ---------------- K6: normalize + leaky + max_k + proj ----------------
__global__ __launch_bounds__(256) void k6_point(const float* __restrict__ f0,
        const int* __restrict__ nidx, const float* __restrict__ w_graph,
        const float* __restrict__ gmu, const float* __restrict__ gn_g,
        const float* __restrict__ gn_b, const float* __restrict__ w_proj,
        const float* __restrict__ b_proj, float* __restrict__ f) {
    __shared__ float wgT[16*64];
    __shared__ float wpT[64*64];
    __shared__ float feat[4][8][16];
    __shared__ float gmax_s[4][64];
    int t = threadIdx.x;
    for (int i=t; i<1024; i+=256) wgT[(i&15)*64 + (i>>4)] = w_graph[i];
    for (int i=t; i<4096; i+=256) wpT[(i&63)*64 + (i>>6)] = w_proj[i];
    int blk = blockIdx.x;
    int b = blk >> 9, n0 = (blk & 511)*4;
    build_feat(t, b, n0, f0, nidx, feat);
    __syncthreads();
    int pt = t >> 6, o = t & 63;
    int grp = o >> 4;
    float mu = gmu[(b*4+grp)*2], rsig = gmu[(b*4+grp)*2+1];
    float ga = gn_g[o], be = gn_b[o];
    float gm = -1e30f;
#pragma unroll
    for (int k=0; k<8; ++k) {
        float g = 0.f;
#pragma unroll
        for (int c=0; c<16; ++c) g = fmaf(feat[pt][k][c], wgT[c*64+o], g);
        float v = (g - mu)*rsig*ga + be;
        v = (v >= 0.f) ? v : 0.2f*v;
        gm = fmaxf(gm, v);
    }
    gmax_s[pt][o] = gm;
    __syncthreads();
    float acc = b_proj[o];
#pragma unroll
    for (int c=0; c<64; ++c) acc = fmaf(gmax_s[pt][c], wpT[c*64+o], acc);
    f[((size_t)b*NN + n0 + pt)*64 + o] = acc;
}

// ---------------- K7: scatter-sum onto NHWC grid (all batches) -----------
__global__ __launch_bounds__(256) void k7_scatter(const float* __restrict__ f,
        const int* __restrict__ lin, float* __restrict__ res) {
    int blk = blockIdx.x, t = threadIdx.x;
    int b = blk >> 9;
    int n = (blk & 511)*4 + (t >> 6);
    int o = t & 63;
    size_t bn = (size_t)b*NN + n;
    float v = f[bn*64 + o];
#pragma unroll
    for (int j=0; j<9; ++j) {
        int cell = lin[bn*9 + j];
        if (cell >= 0 && cell < HWD)
            atomicAdd(&res[((size_t)b*HWD + cell)*64 + o], v);
    }
}

// ---------------- K8: conv3x3 + scale/shift + relu (NHWC) ----------------
// R12 PMC: VALUBusy 28% — the weight loads wp[c*64+oo] were VECTOR global
// loads (compiler can't prove t>>6 wave-uniform) stalling on vmcnt in the
// hot loop. readfirstlane makes the pointer scalar -> s_load broadcasts on
// the scalar pipe; unroll 4 batches the ds_reads ahead of the FMA block.
__global__ __launch_bounds__(256) void k8_conv1(const float* __restrict__ src,
        const float* __restrict__ wt, const float* __restrict__ g1,
        const float* __restrict__ b1, float* __restrict__ dst) {
    __shared__ float smem[180*65];
    int x0 = blockIdx.x*16, y0 = blockIdx.y*8, b = blockIdx.z;
    int t = threadIdx.x;
    const float* sp = src + (size_t)b*HWD*64;
    for (int i=t; i<2880; i+=256) {
        int cell = i >> 4, c4 = i & 15;
        int gy = y0 - 1 + cell/18, gx = x0 - 1 + cell%18;
        float4 v = make_float4(0.f,0.f,0.f,0.f);
        if (gy >= 0 && gy < OBJ && gx >= 0 && gx < OBJ)
            v = *(const float4*)(sp + ((size_t)gy*OBJ + gx)*64 + c4*4);
        float* d = &smem[cell*65 + c4*4];
        d[0]=v.x; d[1]=v.y; d[2]=v.z; d[3]=v.w;
    }
    __syncthreads();
    int lane = t & 63, ob = (t >> 6)*16;
    int obs = __builtin_amdgcn_readfirstlane(ob);   // scalarize weight pointer
    int py = lane >> 3, px = lane & 7;
    float accA[16], accB[16];
#pragma unroll
    for (int i=0; i<16; ++i) { accA[i]=0.f; accB[i]=0.f; }
#pragma unroll
    for (int dy=0; dy<3; ++dy)
#pragma unroll
    for (int dx=0; dx<3; ++dx) {
        int ca = (py+dy)*18 + (px+dx);
        const float* wp = wt + (dy*3+dx)*4096 + obs;
#pragma unroll 4
        for (int c=0; c<64; ++c) {
            float ia = smem[ca*65 + c];
            float ib = smem[(ca+8)*65 + c];
            const float* wr = wp + c*64;
#pragma unroll
            for (int oo=0; oo<16; ++oo) {
                float wv = wr[oo];
                accA[oo] = fmaf(ia, wv, accA[oo]);
                accB[oo] = fmaf(ib, wv, accB[oo]);
            }
        }
    }
    size_t baseA = ((size_t)b*HWD + (size_t)(y0+py)*OBJ + (x0+px))*64 + ob;
    float* dA = dst + baseA;
    float* dB = dA + 8*64;
#pragma unroll
    for (int q=0; q<4; ++q) {
        float4 va, vb;
        float* pa = (float*)&va; float* pb = (float*)&vb;
#pragma unroll
        for (int j=0; j<4; ++j) {
            int oo = q*4 + j;
            pa[j] = fmaxf(fmaf(accA[oo], g1[ob+oo], b1[ob+oo]), 0.f);
            pb[j] = fmaxf(fmaf(accB[oo], g1[ob+oo], b1[ob+oo]), 0.f);
        }
        ((float4*)dA)[q] = va;
        ((float4*)dB)[q] = vb;
    }
}

// ---------------- K9: conv3x3 + bn + residual-relu + blkout + img head ---
__global__ __launch_bounds__(256) void k9_conv2(const float* __restrict__ h1,
        const float* __restrict__ wt, const float* __restrict__ g2,
        const float* __restrict__ b2, const float* __restrict__ res,
        const float* __restrict__ wbk, const float* __restrict__ bbk,
        const float* __restrict__ wim, const float* __restrict__ bim,
        float* __restrict__ out) {
    __shared__ float smem[12480];
    int x0 = blockIdx.x*16, y0 = blockIdx.y*8, b = blockIdx.z;
    int t = threadIdx.x;
    const float* sp = h1 + (size_t)b*HWD*64;
    for (int i=t; i<2880; i+=256) {
        int cell = i >> 4, c4 = i & 15;
        int gy = y0 - 1 + cell/18, gx = x0 - 1 + cell%18;
        float4 v = make_float4(0.f,0.f,0.f,0.f);
        if (gy >= 0 && gy < OBJ && gx >= 0 && gx < OBJ)
            v = *(const float4*)(sp + ((size_t)gy*OBJ + gx)*64 + c4*4);
        float* d = &smem[cell*65 + c4*4];
        d[0]=v.x; d[1]=v.y; d[2]=v.z; d[3]=v.w;
    }
    __syncthreads();
    int lane = t & 63, ob = (t >> 6)*16;
    int obs = __builtin_amdgcn_readfirstlane(ob);   // scalarize weight pointer
    int py = lane >> 3, px = lane & 7;
    float accA[16], accB[16];
#pragma unroll
    for (int i=0; i<16; ++i) { accA[i]=0.f; accB[i]=0.f; }
#pragma unroll
    for (int dy=0; dy<3; ++dy)
#pragma unroll
    for (int dx=0; dx<3; ++dx) {
        int ca = (py+dy)*18 + (px+dx);
        const float* wp = wt + (dy*3+dx)*4096 + obs;
#pragma unroll 4
        for (int c=0; c<64; ++c) {
            float ia = smem[ca*65 + c];
            float ib = smem[(ca+8)*65 + c];
            const float* wr = wp + c*64;
#pragma unroll
            for (int oo=0; oo<16; ++oo) {
                float wv = wr[oo];
                accA[oo] = fmaf(ia, wv, accA[oo]);
                accB[oo] = fmaf(ib, wv, accB[oo]);
            }
        }
    }
    size_t baseA = ((size_t)b*HWD + (size_t)(y0+py)*OBJ + (x0+px))*64 + ob;
    const float4* rA = (const float4*)(res + baseA);
    const float4* rB = (const float4*)(res + baseA + 8*64);
#pragma unroll
    for (int q=0; q<4; ++q) {
        float4 va = rA[q], vb = rB[q];
        const float* pa = (const float*)&va; const float* pb = (const float*)&vb;
#pragma unroll
        for (int j=0; j<4; ++j) {
            int oo = q*4 + j;
            accA[oo] = fmaxf(fmaf(accA[oo], g2[ob+oo], b2[ob+oo]) + pa[j], 0.f);
            accB[oo] = fmaxf(fmaf(accB[oo], g2[ob+oo], b2[ob+oo]) + pb[j], 0.f);
        }
    }
    __syncthreads();
    for (int i=t; i<4096; i+=256) smem[8320 + (i&63)*64 + (i>>6)] = wbk[i];

    const float MEAN[3] = {0.485f, 0.456f, 0.406f};
    const float STDV[3] = {0.229f, 0.224f, 0.225f};
    int pixid = py*8 + px;
    float* treg = smem;
    float* ureg = smem + 4160;
    const float* wbkT = smem + 8320;
#pragma unroll
    for (int h=0; h<2; ++h) {
#pragma unroll
        for (int oo=0; oo<16; ++oo)
            treg[pixid*65 + ob + oo] = (h == 0) ? accA[oo] : accB[oo];
        __syncthreads();
        {
            int pix = t & 63, grp = t >> 6;
            float u[16];
#pragma unroll
            for (int oo=0; oo<16; ++oo) u[oo] = bbk[grp*16 + oo];
            for (int c=0; c<64; ++c) {
                float tv = treg[pix*65 + c];
                const float* wr = wbkT + c*64 + grp*16;
#pragma unroll
                for (int oo=0; oo<16; ++oo) u[oo] = fmaf(tv, wr[oo], u[oo]);
            }
#pragma unroll
            for (int oo=0; oo<16; ++oo) ureg[pix*65 + grp*16 + oo] = u[oo];
        }
        __syncthreads();
        if (t < 192) {
            int o = t >> 6, pix = t & 63;
            float s = bim[o];
            for (int c=0; c<64; ++c) s = fmaf(wim[o*64 + c], ureg[pix*65 + c], s);
            float sig = 1.f / (1.f + expf(-s));
            float v = (sig - MEAN[o]) / STDV[o];
            int ppy = pix >> 3, ppx = pix & 7;
            out[((size_t)(b*3 + o))*HWD + (size_t)(y0+ppy)*OBJ + x0 + h*8 + ppx] = v;
        }
        __syncthreads();
    }
}

// ---------------- launch ----------------
extern "C" void kernel_launch(void* const* d_in, const int* in_sizes, int n_in,
                              void* d_out, int out_size, void* d_ws, size_t ws_size,
                              hipStream_t stream) {
    const float* pc      = (const float*)d_in[0];
    const float* w_in    = (const float*)d_in[1];
    const float* b_in    = (const float*)d_in[2];
    const float* w_graph = (const float*)d_in[3];
    const float* gn_g    = (const float*)d_in[4];
    const float* gn_b    = (const float*)d_in[5];
    const float* w_proj  = (const float*)d_in[6];
    const float* b_proj  = (const float*)d_in[7];
    const float* bb_w1   = (const float*)d_in[8];
    const float* bb_g1   = (const float*)d_in[9];
    const float* bb_b1   = (const float*)d_in[10];
    const float* bb_w2   = (const float*)d_in[11];
    const float* bb_g2   = (const float*)d_in[12];
    const float* bb_b2   = (const float*)d_in[13];
    const float* w_blkout= (const float*)d_in[14];
    const float* b_blkout= (const float*)d_in[15];
    const float* w_img   = (const float*)d_in[16];
    const float* b_img   = (const float*)d_in[17];

    float* ws     = (float*)d_ws;
    float* res    = ws + RES_OFF;
    float* h1     = ws + H1_OFF;
    float* pd     = ws + H1_OFF;
    int*   pi     = (int*)(ws + H1_OFF + (size_t)BB*NN*SEG*KNNK);
    float* f      = ws + F_OFF;
    float* f0     = ws + F0_OFF;
    float* bparam = ws + BP_OFF;
    float* gsum   = ws + GS_OFF;
    float* gmu    = ws + GM_OFF;
    float* wt1    = ws + WT1_OFF;
    float* wt2    = ws + WT2_OFF;
    int*   lin    = (int*)(ws + INT_OFF);
    int*   nidx   = lin + (size_t)BB*NN*9;
    float* out    = (float*)d_out;

    hipMemsetAsync(res, 0, RES_SZ*sizeof(float), stream);
    hipMemsetAsync(gsum, 0, 64*sizeof(float), stream);

    k0_wt<<<144, 256, 0, stream>>>(bb_w1, wt1);
    k0_wt<<<144, 256, 0, stream>>>(bb_w2, wt2);
    k1_params<<<BB, 256, 0, stream>>>(pc, bparam);
    k2_lin<<<(BB*NN)/256, 256, 0, stream>>>(pc, bparam, lin);
    k3_f0<<<(BB*NN*8)/256, 256, 0, stream>>>(pc, w_in, b_in, f0);
    k4_knn<<<dim3(NN/256, BB, SEG), 256, 0, stream>>>(pc, pd, pi);
    k4b_merge<<<(BB*NN)/256, 256, 0, stream>>>(pd, pi, nidx);
    k5_stats<<<(BB*NN)/4, 256, 0, stream>>>(f0, nidx, w_graph, gsum);
    k5b_finalize<<<1, 64, 0, stream>>>(gsum, gmu);
    k6_point<<<(BB*NN)/4, 256, 0, stream>>>(f0, nidx, w_graph, gmu, gn_g, gn_b,
                                            w_proj, b_proj, f);
    k7_scatter<<<(BB*NN)/4, 256, 0, stream>>>(f, lin, res);
    k8_conv1<<<dim3(14, 28, BB), 256, 0, stream>>>(res, wt1, bb_g1, bb_b1, h1);
    k9_conv2<<<dim3(14, 28, BB), 256, 0, stream>>>(h1, wt2, bb_g2, bb_b2, res,
                                                   w_blkout, b_blkout, w_img, b_img, out);
}